// Round 3
// baseline (127.068 us; speedup 1.0000x reference)
//
#include <hip/hip_runtime.h>
#include <hip/hip_bf16.h>

// Problem constants
constexpr int Dd = 1024;           // feature dim
constexpr int Tt = 2048;           // sequence length
constexpr int Bb = 4;              // batch
constexpr int Rr = Bb * Tt;        // GEMM rows = 8192
constexpr int NCH = 32;            // scan chunks per batch row
constexpr int CL  = 64;            // rows written per scan block
constexpr int HOR = 32;            // truncated carry horizon (d^32 = 1.8e-5)
constexpr int SCB = Bb * NCH * 2;  // 256 scan blocks (x2 d-halves)
constexpr int CBL = 64;            // c-reduction blocks
constexpr int WBL = 512;           // W-build blocks

typedef __attribute__((ext_vector_type(2))) float f32x2;
typedef __attribute__((ext_vector_type(4))) float f32x4;
typedef __attribute__((ext_vector_type(16))) float f32x16;
typedef __attribute__((ext_vector_type(8))) short bf16x8;

__device__ __forceinline__ float sigmoidf_(float v) {
    return 1.0f / (1.0f + expf(-v));
}

__device__ __forceinline__ short bf16bits(float f) {
    union { __hip_bfloat16 b; short s; } u;
    u.b = __float2bfloat16(f);
    return u.s;
}

__device__ __forceinline__ void async16(const void* g, void* l) {
    __builtin_amdgcn_global_load_lds(
        (const __attribute__((address_space(1))) unsigned int*)g,
        (__attribute__((address_space(3))) unsigned int*)l,
        16, 0, 0);
}

// ---------------------------------------------------------------------------
// Kernel 1: blocks [0,64): circulant c[n] = sum_m unbind[m]*bind[(m+n)%D]
//   (dispatched first so they don't extend the scan tail).
//   blocks [64,320): truncated-horizon scan, CL=64 rows per block,
//   d-split in halves (thread owns 2 consecutive d of one 512-col half).
//   x re-read factor 1.5x.
// grid 320 x 256
__global__ void k_scan(const float* __restrict__ x,
                       const float* __restrict__ bind,
                       const float* __restrict__ unbind,
                       const float* __restrict__ decay,
                       __hip_bfloat16* __restrict__ xs,
                       float* __restrict__ c) {
    __shared__ float sb[Dd];
    __shared__ float su[Dd];
    __shared__ float sp[256];

    const int tid = threadIdx.x;
    if (blockIdx.x >= CBL) {
        const int sid = blockIdx.x - CBL;
        const int dh = sid & 1;
        const int ch = (sid >> 1) & (NCH - 1);
        const int b  = sid >> 6;
        const float dd = sigmoidf_(decay[0]);
        const int t0 = ch * CL;
        const int d  = dh * 512 + tid * 2;
        f32x2 h = (f32x2){0.f, 0.f};
        if (ch != 0) {
            const size_t pb = ((size_t)b * Tt + (size_t)(t0 - HOR)) * Dd + d;
            #pragma unroll 8
            for (int t = 0; t < HOR; ++t) {
                f32x2 v = *(const f32x2*)&x[pb + (size_t)t * Dd];
                h = dd * h + v;
            }
        }
        const size_t base = ((size_t)b * Tt + (size_t)t0) * Dd + d;
        #pragma unroll 8
        for (int t = 0; t < CL; ++t) {
            f32x2 v = *(const f32x2*)&x[base + (size_t)t * Dd];
            h = dd * h + v;
            ushort2 o;
            o.x = (unsigned short)bf16bits(h[0]);
            o.y = (unsigned short)bf16bits(h[1]);
            *(ushort2*)&xs[base + (size_t)t * Dd] = o;
        }
    } else {
        for (int j = tid; j < Dd; j += 256) { sb[j] = bind[j]; su[j] = unbind[j]; }
        __syncthreads();
        const int n_loc = tid >> 4;
        const int seg = tid & 15;
        const int n = (int)blockIdx.x * 16 + n_loc;
        float acc = 0.f;
        #pragma unroll 8
        for (int i = 0; i < 64; ++i) {
            const int m = i * 16 + seg;
            acc = fmaf(su[m], sb[(m + n) & (Dd - 1)], acc);
        }
        sp[tid] = acc;
        __syncthreads();
        if (tid < 16) {
            float s = 0.f;
            #pragma unroll
            for (int j = 0; j < 16; ++j) s += sp[tid * 16 + j];
            c[(int)blockIdx.x * 16 + tid] = s;
        }
    }
}

// ---------------------------------------------------------------------------
// Kernel 2: Wt[n][k] = bf16(c[(n-k) mod D]); 8 outputs/thread, c is L2-hot.
// grid 512 x 256
__global__ void k_wb(const float* __restrict__ c,
                     __hip_bfloat16* __restrict__ wt) {
    const int idx8 = blockIdx.x * 256 + threadIdx.x;
    const int n = idx8 >> 7;
    const int k0 = (idx8 & 127) * 8;
    bf16x8 v;
    #pragma unroll
    for (int j = 0; j < 8; ++j)
        v[j] = bf16bits(c[(n - (k0 + j)) & (Dd - 1)]);
    *(bf16x8*)&wt[(size_t)n * Dd + k0] = v;
}

// ---------------------------------------------------------------------------
// Kernel 3: out = x + g*(xs @ Wt^T).  128x128 tile, BK=64, 4 waves 2x2,
// 32x32x16 bf16 MFMA.  XOR chunk swizzle (R9-verified): 16B chunk j of row r
// stored at physical chunk j^(r&7) -> conflict-free b128 fragment reads while
// keeping global_load_lds staging contiguous.
//
//  * double-buffered LDS, single __syncthreads per K-step: stage(next) is
//    issued BEFORE ds_read+MFMA of current, so global_load_lds latency hides
//    under ~512 cyc of compute (T3-minimum 2-phase).
//  * XCD-grouped block mapping on a FLAT 512-block grid (R2 fix: grid was
//    (64,8) while the mapping assumed flat 0..511 -> 7/8 of tiles unwritten).
//    id = xcd + 8*(tn + 8*gg); the 8 tile_n consumers of one A-panel share
//    id&7 -> same XCD; per-XCD L2 working set = 8 A-panels (2MB) + Wt (2MB).
// grid 512 x 256
__global__ __launch_bounds__(256) void k_gemm(
    const __hip_bfloat16* __restrict__ A,   // [R][D] bf16 (scanned x)
    const __hip_bfloat16* __restrict__ Wt,  // [D][D] bf16, Wt[n][k]
    const float* __restrict__ x,            // [R][D] fp32
    const float* __restrict__ gate,         // [1]
    float* __restrict__ out)                // [R][D] fp32
{
    __shared__ __align__(16) __hip_bfloat16 sA[2][128 * 64];
    __shared__ __align__(16) __hip_bfloat16 sB[2][128 * 64];

    const int tid = threadIdx.x;
    const int wave = tid >> 6;
    const int lane = tid & 63;

    // XCD-grouped mapping (id%8 assumed round-robin over 8 XCDs; perf-only).
    const int id  = blockIdx.x;        // 0..511 (flat grid)
    const int xcd = id & 7;
    const int rr  = id >> 3;           // 0..63
    const int tn  = rr & 7;            // tile_n index
    const int gg  = rr >> 3;           // 0..7
    const int tile_m = (xcd * 8 + gg) * 128;
    const int tile_n = tn * 128;

    const int wm = (wave & 1) * 64;
    const int wn = (wave >> 1) * 64;

    f32x16 acc[2][2];
    #pragma unroll
    for (int i = 0; i < 2; ++i)
        #pragma unroll
        for (int j = 0; j < 2; ++j)
            #pragma unroll
            for (int e = 0; e < 16; ++e)
                acc[i][j][e] = 0.f;

    const int r8 = lane >> 3;
    const int gchunk = (lane & 7) ^ (r8 & 7);
    const int fm  = lane & 31;         // fragment m/n index
    const int fsw = fm & 7;            // row-part of the read swizzle
    const int fc0 = lane >> 5;         // logical chunk low bit (k half)

    // stage one 128x64 A-tile + B-tile into buffer `buf` (buf is a literal
    // at every call site so LDS addressing stays compile-time).
    auto stage = [&](int buf, int k0) {
        #pragma unroll
        for (int j = 0; j < 4; ++j) {
            const int row = wave * 32 + j * 8;  // wave-uniform
            async16(A  + (size_t)(tile_m + row + r8) * Dd + k0 + gchunk * 8,
                    &sA[buf][row * 64]);
            async16(Wt + (size_t)(tile_n + row + r8) * Dd + k0 + gchunk * 8,
                    &sB[buf][row * 64]);
        }
    };

    auto compute = [&](int buf) {
        bf16x8 af[2][4], bfr[2][4];
        #pragma unroll
        for (int sm = 0; sm < 2; ++sm)
            #pragma unroll
            for (int kh = 0; kh < 4; ++kh)
                af[sm][kh] = *(const bf16x8*)
                    &sA[buf][(wm + sm * 32 + fm) * 64 + ((kh * 2 + fc0) ^ fsw) * 8];
        #pragma unroll
        for (int sn = 0; sn < 2; ++sn)
            #pragma unroll
            for (int kh = 0; kh < 4; ++kh)
                bfr[sn][kh] = *(const bf16x8*)
                    &sB[buf][(wn + sn * 32 + fm) * 64 + ((kh * 2 + fc0) ^ fsw) * 8];

        #pragma unroll
        for (int kh = 0; kh < 4; ++kh)
            #pragma unroll
            for (int sm = 0; sm < 2; ++sm)
                #pragma unroll
                for (int sn = 0; sn < 2; ++sn)
                    acc[sm][sn] = __builtin_amdgcn_mfma_f32_32x32x16_bf16(
                        af[sm][kh], bfr[sn][kh], acc[sm][sn], 0, 0, 0);
    };

    // 2-phase pipeline, manually unrolled x2 so buffer indices are literals.
    stage(0, 0);
    __syncthreads();                   // drains vmcnt -> buf0 ready
    for (int step = 0; step < Dd / 64; step += 2) {
        stage(1, (step + 1) * 64);     // issue next-tile loads (step+1 <= 15)
        compute(0);
        __syncthreads();               // drain -> buf1 ready, buf0 reads done
        if (step + 2 < Dd / 64)
            stage(0, (step + 2) * 64);
        compute(1);
        __syncthreads();               // drain -> buf0 ready, buf1 reads done
    }

    // C/D layout (R7-verified): col = lane&31, row = (reg&3)+8*(reg>>2)+4*(lane>>5)
    const float g = gate[0];
    #pragma unroll
    for (int sm = 0; sm < 2; ++sm) {
        #pragma unroll
        for (int sn = 0; sn < 2; ++sn) {
            const int colg = tile_n + wn + sn * 32 + (lane & 31);
            #pragma unroll
            for (int g1 = 0; g1 < 4; ++g1) {
                const int row0 = tile_m + wm + sm * 32 + g1 * 8 + (lane >> 5) * 4;
                #pragma unroll
                for (int r0 = 0; r0 < 4; ++r0) {
                    const size_t off = (size_t)(row0 + r0) * Dd + colg;
                    out[off] = fmaf(g, acc[sm][sn][g1 * 4 + r0], x[off]);
                }
            }
        }
    }
}

// ---------------------------------------------------------------------------
extern "C" void kernel_launch(void* const* d_in, const int* in_sizes, int n_in,
                              void* d_out, int out_size, void* d_ws, size_t ws_size,
                              hipStream_t stream) {
    const float* x      = (const float*)d_in[0];
    const float* bind   = (const float*)d_in[1];
    const float* unbind = (const float*)d_in[2];
    const float* gate   = (const float*)d_in[3];
    const float* decay  = (const float*)d_in[4];
    float* out = (float*)d_out;

    // workspace layout (~18.8 MB)
    char* ws = (char*)d_ws;
    __hip_bfloat16* wt = (__hip_bfloat16*)ws;                            // 2 MB
    __hip_bfloat16* xs = (__hip_bfloat16*)(ws + (size_t)Dd * Dd * 2);    // 16.8 MB
    float* c = (float*)(ws + (size_t)Dd * Dd * 2 + (size_t)Rr * Dd * 2); // 4 KB

    k_scan<<<dim3(SCB + CBL), dim3(256), 0, stream>>>(x, bind, unbind, decay, xs, c);
    k_wb  <<<dim3(WBL),       dim3(256), 0, stream>>>(c, wt);
    k_gemm<<<dim3(512),       dim3(256), 0, stream>>>(xs, wt, x, gate, out);
}

// Round 4
// 124.088 us; speedup vs baseline: 1.0240x; 1.0240x over previous
//
#include <hip/hip_runtime.h>
#include <hip/hip_bf16.h>

// Problem constants
constexpr int Dd = 1024;           // feature dim
constexpr int Tt = 2048;           // sequence length
constexpr int Bb = 4;              // batch
constexpr int Rr = Bb * Tt;        // GEMM rows = 8192
constexpr int NCH = 32;            // scan chunks per batch row
constexpr int CL  = 64;            // rows written per scan block
constexpr int HOR = 32;            // truncated carry horizon (d^32 = 1.8e-5)
constexpr int SCB = Bb * NCH * 2;  // 256 scan blocks (x2 d-halves)
constexpr int CBL = 64;            // c-reduction blocks
constexpr int WBL = 512;           // W-build blocks

typedef __attribute__((ext_vector_type(2))) float f32x2;
typedef __attribute__((ext_vector_type(4))) float f32x4;
typedef __attribute__((ext_vector_type(16))) float f32x16;
typedef __attribute__((ext_vector_type(8))) short bf16x8;

__device__ __forceinline__ float sigmoidf_(float v) {
    return 1.0f / (1.0f + expf(-v));
}

__device__ __forceinline__ short bf16bits(float f) {
    union { __hip_bfloat16 b; short s; } u;
    u.b = __float2bfloat16(f);
    return u.s;
}

__device__ __forceinline__ void async16(const void* g, void* l) {
    __builtin_amdgcn_global_load_lds(
        (const __attribute__((address_space(1))) unsigned int*)g,
        (__attribute__((address_space(3))) unsigned int*)l,
        16, 0, 0);
}

// ---------------------------------------------------------------------------
// Kernel 1: blocks [0,64): circulant c[n] = sum_m unbind[m]*bind[(m+n)%D]
//   (dispatched first so they don't extend the scan tail).
//   blocks [64,320): truncated-horizon scan, CL=64 rows per block,
//   d-split in halves (thread owns 2 consecutive d of one 512-col half).
//   x re-read factor 1.5x.
// grid 320 x 256
__global__ void k_scan(const float* __restrict__ x,
                       const float* __restrict__ bind,
                       const float* __restrict__ unbind,
                       const float* __restrict__ decay,
                       __hip_bfloat16* __restrict__ xs,
                       float* __restrict__ c) {
    __shared__ float sb[Dd];
    __shared__ float su[Dd];
    __shared__ float sp[256];

    const int tid = threadIdx.x;
    if (blockIdx.x >= CBL) {
        const int sid = blockIdx.x - CBL;
        const int dh = sid & 1;
        const int ch = (sid >> 1) & (NCH - 1);
        const int b  = sid >> 6;
        const float dd = sigmoidf_(decay[0]);
        const int t0 = ch * CL;
        const int d  = dh * 512 + tid * 2;
        f32x2 h = (f32x2){0.f, 0.f};
        if (ch != 0) {
            const size_t pb = ((size_t)b * Tt + (size_t)(t0 - HOR)) * Dd + d;
            #pragma unroll 8
            for (int t = 0; t < HOR; ++t) {
                f32x2 v = *(const f32x2*)&x[pb + (size_t)t * Dd];
                h = dd * h + v;
            }
        }
        const size_t base = ((size_t)b * Tt + (size_t)t0) * Dd + d;
        #pragma unroll 8
        for (int t = 0; t < CL; ++t) {
            f32x2 v = *(const f32x2*)&x[base + (size_t)t * Dd];
            h = dd * h + v;
            ushort2 o;
            o.x = (unsigned short)bf16bits(h[0]);
            o.y = (unsigned short)bf16bits(h[1]);
            *(ushort2*)&xs[base + (size_t)t * Dd] = o;
        }
    } else {
        for (int j = tid; j < Dd; j += 256) { sb[j] = bind[j]; su[j] = unbind[j]; }
        __syncthreads();
        const int n_loc = tid >> 4;
        const int seg = tid & 15;
        const int n = (int)blockIdx.x * 16 + n_loc;
        float acc = 0.f;
        #pragma unroll 8
        for (int i = 0; i < 64; ++i) {
            const int m = i * 16 + seg;
            acc = fmaf(su[m], sb[(m + n) & (Dd - 1)], acc);
        }
        sp[tid] = acc;
        __syncthreads();
        if (tid < 16) {
            float s = 0.f;
            #pragma unroll
            for (int j = 0; j < 16; ++j) s += sp[tid * 16 + j];
            c[(int)blockIdx.x * 16 + tid] = s;
        }
    }
}

// ---------------------------------------------------------------------------
// Kernel 2: Wt[n][k] = bf16(c[(n-k) mod D]); 8 outputs/thread, c is L2-hot.
// grid 512 x 256
__global__ void k_wb(const float* __restrict__ c,
                     __hip_bfloat16* __restrict__ wt) {
    const int idx8 = blockIdx.x * 256 + threadIdx.x;
    const int n = idx8 >> 7;
    const int k0 = (idx8 & 127) * 8;
    bf16x8 v;
    #pragma unroll
    for (int j = 0; j < 8; ++j)
        v[j] = bf16bits(c[(n - (k0 + j)) & (Dd - 1)]);
    *(bf16x8*)&wt[(size_t)n * Dd + k0] = v;
}

// ---------------------------------------------------------------------------
// Kernel 3: out = x + g*(xs @ Wt^T).  128x128 tile, BK=64, 4 waves 2x2,
// 32x32x16 bf16 MFMA.  XOR chunk swizzle (R9-verified): 16B chunk j of row r
// stored at physical chunk j^(r&7) -> conflict-free b128 fragment reads while
// keeping global_load_lds staging contiguous.
//
// R4: single-buffered again (R3's 64KB dbuf halved occupancy to 2 blocks/CU
// and regressed — inter-block wave overlap at 3-4 blocks/CU already hides
// staging latency, per m114).  Kept from R3: flat-512 XCD-grouped mapping.
// New: per-kh fragment loads (shorter live ranges) + launch_bounds(256,3).
// grid 512 x 256
__global__ __launch_bounds__(256, 3) void k_gemm(
    const __hip_bfloat16* __restrict__ A,   // [R][D] bf16 (scanned x)
    const __hip_bfloat16* __restrict__ Wt,  // [D][D] bf16, Wt[n][k]
    const float* __restrict__ x,            // [R][D] fp32
    const float* __restrict__ gate,         // [1]
    float* __restrict__ out)                // [R][D] fp32
{
    __shared__ __align__(16) __hip_bfloat16 sA[128 * 64];
    __shared__ __align__(16) __hip_bfloat16 sB[128 * 64];

    const int tid = threadIdx.x;
    const int wave = tid >> 6;
    const int lane = tid & 63;

    // XCD-grouped mapping on flat grid (id%8 assumed XCD round-robin).
    // id = xcd + 8*(tn + 8*gg); 8 tile_n consumers of one A-panel share an
    // XCD; per-XCD L2 working set = 8 A-panels (2MB) + Wt (2MB) = 4MB L2.
    const int id  = blockIdx.x;        // 0..511 (flat grid)
    const int xcd = id & 7;
    const int rr  = id >> 3;           // 0..63
    const int tn  = rr & 7;            // tile_n index
    const int gg  = rr >> 3;           // 0..7
    const int tile_m = (xcd * 8 + gg) * 128;
    const int tile_n = tn * 128;

    const int wm = (wave & 1) * 64;
    const int wn = (wave >> 1) * 64;

    f32x16 acc[2][2];
    #pragma unroll
    for (int i = 0; i < 2; ++i)
        #pragma unroll
        for (int j = 0; j < 2; ++j)
            #pragma unroll
            for (int e = 0; e < 16; ++e)
                acc[i][j][e] = 0.f;

    const int r8 = lane >> 3;
    const int gchunk = (lane & 7) ^ (r8 & 7);
    const int fm  = lane & 31;         // fragment m/n index
    const int fsw = fm & 7;            // row-part of the read swizzle
    const int fc0 = lane >> 5;         // logical chunk low bit (k half)

    for (int k0 = 0; k0 < Dd; k0 += 64) {
        __syncthreads();               // prior iteration's reads complete
        #pragma unroll
        for (int j = 0; j < 4; ++j) {
            const int row = wave * 32 + j * 8;  // wave-uniform
            async16(A  + (size_t)(tile_m + row + r8) * Dd + k0 + gchunk * 8,
                    &sA[row * 64]);
            async16(Wt + (size_t)(tile_n + row + r8) * Dd + k0 + gchunk * 8,
                    &sB[row * 64]);
        }
        __syncthreads();               // drain vmcnt -> tiles visible

        #pragma unroll
        for (int kh = 0; kh < 4; ++kh) {
            bf16x8 af[2], bfr[2];
            #pragma unroll
            for (int sm = 0; sm < 2; ++sm)
                af[sm] = *(const bf16x8*)
                    &sA[(wm + sm * 32 + fm) * 64 + ((kh * 2 + fc0) ^ fsw) * 8];
            #pragma unroll
            for (int sn = 0; sn < 2; ++sn)
                bfr[sn] = *(const bf16x8*)
                    &sB[(wn + sn * 32 + fm) * 64 + ((kh * 2 + fc0) ^ fsw) * 8];
            #pragma unroll
            for (int sm = 0; sm < 2; ++sm)
                #pragma unroll
                for (int sn = 0; sn < 2; ++sn)
                    acc[sm][sn] = __builtin_amdgcn_mfma_f32_32x32x16_bf16(
                        af[sm], bfr[sn], acc[sm][sn], 0, 0, 0);
        }
    }

    // C/D layout (R7-verified): col = lane&31, row = (reg&3)+8*(reg>>2)+4*(lane>>5)
    const float g = gate[0];
    #pragma unroll
    for (int sm = 0; sm < 2; ++sm) {
        #pragma unroll
        for (int sn = 0; sn < 2; ++sn) {
            const int colg = tile_n + wn + sn * 32 + (lane & 31);
            #pragma unroll
            for (int g1 = 0; g1 < 4; ++g1) {
                const int row0 = tile_m + wm + sm * 32 + g1 * 8 + (lane >> 5) * 4;
                #pragma unroll
                for (int r0 = 0; r0 < 4; ++r0) {
                    const size_t off = (size_t)(row0 + r0) * Dd + colg;
                    out[off] = fmaf(g, acc[sm][sn][g1 * 4 + r0], x[off]);
                }
            }
        }
    }
}

// ---------------------------------------------------------------------------
extern "C" void kernel_launch(void* const* d_in, const int* in_sizes, int n_in,
                              void* d_out, int out_size, void* d_ws, size_t ws_size,
                              hipStream_t stream) {
    const float* x      = (const float*)d_in[0];
    const float* bind   = (const float*)d_in[1];
    const float* unbind = (const float*)d_in[2];
    const float* gate   = (const float*)d_in[3];
    const float* decay  = (const float*)d_in[4];
    float* out = (float*)d_out;

    // workspace layout (~18.8 MB)
    char* ws = (char*)d_ws;
    __hip_bfloat16* wt = (__hip_bfloat16*)ws;                            // 2 MB
    __hip_bfloat16* xs = (__hip_bfloat16*)(ws + (size_t)Dd * Dd * 2);    // 16.8 MB
    float* c = (float*)(ws + (size_t)Dd * Dd * 2 + (size_t)Rr * Dd * 2); // 4 KB

    k_scan<<<dim3(SCB + CBL), dim3(256), 0, stream>>>(x, bind, unbind, decay, xs, c);
    k_wb  <<<dim3(WBL),       dim3(256), 0, stream>>>(c, wt);
    k_gemm<<<dim3(512),       dim3(256), 0, stream>>>(xs, wt, x, gate, out);
}

// Round 5
// 122.688 us; speedup vs baseline: 1.0357x; 1.0114x over previous
//
#include <hip/hip_runtime.h>
#include <hip/hip_bf16.h>

// Problem constants
constexpr int Dd = 1024;           // feature dim
constexpr int Tt = 2048;           // sequence length
constexpr int Bb = 4;              // batch
constexpr int Rr = Bb * Tt;        // GEMM rows = 8192
constexpr int NCH = 32;            // scan chunks per batch row
constexpr int CL  = 64;            // rows written per scan block
constexpr int HOR = 32;            // truncated carry horizon (d^32 = 1.8e-5)
constexpr int SCB = Bb * NCH * 2;  // 256 scan blocks (x2 d-halves)
constexpr int CBL = 64;            // c-reduction blocks
constexpr int RSN = 1032;          // ring entries per shifted copy (1024 + 8 pad)

typedef __attribute__((ext_vector_type(2))) float f32x2;
typedef __attribute__((ext_vector_type(4))) float f32x4;
typedef __attribute__((ext_vector_type(16))) float f32x16;
typedef __attribute__((ext_vector_type(8))) short bf16x8;

__device__ __forceinline__ float sigmoidf_(float v) {
    return 1.0f / (1.0f + expf(-v));
}

__device__ __forceinline__ short bf16bits(float f) {
    union { __hip_bfloat16 b; short s; } u;
    u.b = __float2bfloat16(f);
    return u.s;
}

__device__ __forceinline__ void async16(const void* g, void* l) {
    __builtin_amdgcn_global_load_lds(
        (const __attribute__((address_space(1))) unsigned int*)g,
        (__attribute__((address_space(3))) unsigned int*)l,
        16, 0, 0);
}

// ---------------------------------------------------------------------------
// Kernel 1: blocks [0,64): circulant c[n] = sum_m unbind[m]*bind[(m+n)%D]
//   (dispatched first so they don't extend the scan tail).
//   blocks [64,320): truncated-horizon scan, CL=64 rows per block,
//   d-split in halves (thread owns 2 consecutive d of one 512-col half).
//   x re-read factor 1.5x.
// grid 320 x 256
__global__ void k_scan(const float* __restrict__ x,
                       const float* __restrict__ bind,
                       const float* __restrict__ unbind,
                       const float* __restrict__ decay,
                       __hip_bfloat16* __restrict__ xs,
                       float* __restrict__ c) {
    __shared__ float sb[Dd];
    __shared__ float su[Dd];
    __shared__ float sp[256];

    const int tid = threadIdx.x;
    if (blockIdx.x >= CBL) {
        const int sid = blockIdx.x - CBL;
        const int dh = sid & 1;
        const int ch = (sid >> 1) & (NCH - 1);
        const int b  = sid >> 6;
        const float dd = sigmoidf_(decay[0]);
        const int t0 = ch * CL;
        const int d  = dh * 512 + tid * 2;
        f32x2 h = (f32x2){0.f, 0.f};
        if (ch != 0) {
            const size_t pb = ((size_t)b * Tt + (size_t)(t0 - HOR)) * Dd + d;
            #pragma unroll 8
            for (int t = 0; t < HOR; ++t) {
                f32x2 v = *(const f32x2*)&x[pb + (size_t)t * Dd];
                h = dd * h + v;
            }
        }
        const size_t base = ((size_t)b * Tt + (size_t)t0) * Dd + d;
        #pragma unroll 8
        for (int t = 0; t < CL; ++t) {
            f32x2 v = *(const f32x2*)&x[base + (size_t)t * Dd];
            h = dd * h + v;
            ushort2 o;
            o.x = (unsigned short)bf16bits(h[0]);
            o.y = (unsigned short)bf16bits(h[1]);
            *(ushort2*)&xs[base + (size_t)t * Dd] = o;
        }
    } else {
        for (int j = tid; j < Dd; j += 256) { sb[j] = bind[j]; su[j] = unbind[j]; }
        __syncthreads();
        const int n_loc = tid >> 4;
        const int seg = tid & 15;
        const int n = (int)blockIdx.x * 16 + n_loc;
        float acc = 0.f;
        #pragma unroll 8
        for (int i = 0; i < 64; ++i) {
            const int m = i * 16 + seg;
            acc = fmaf(su[m], sb[(m + n) & (Dd - 1)], acc);
        }
        sp[tid] = acc;
        __syncthreads();
        if (tid < 16) {
            float s = 0.f;
            #pragma unroll
            for (int j = 0; j < 16; ++j) s += sp[tid * 16 + j];
            c[(int)blockIdx.x * 16 + tid] = s;
        }
    }
}

// ---------------------------------------------------------------------------
// Kernel 2: out = x + g*(xs @ Wt^T) with Wt NEVER materialized.
// Wt[n][k] = c[(n-k) mod D] is circulant; the B-operand of each MFMA is 8
// ascending entries of the reversed ring rrev[i] = c[(-i) mod D].  We build
// 8 shift-by-s copies rs[s][t] = rrev[(t+s) mod D] in LDS once per block
// (16.5 KB) so each B fragment is one 16B-aligned ds_read_b128:
//   bi = (k0 + chunk*8 - n) mod D;  frag = rs[bi&7][(bi>>3)*8 .. +7]
// Algebra: rs[bi&7][(bi&~7)+j] = c[(n - k0 - chunk*8 - j) mod D]  (verified).
// A-side unchanged: async16 staging + XOR chunk swizzle (R9-verified),
// single-buffered (R3's dbuf halved occupancy and regressed).
// This removes k_wb (kernel+gap), all B staging (vmcnt drain per K-step
// halves), and ~134 MB aggregate Wt L2 traffic.
// grid 512 x 256
__global__ __launch_bounds__(256, 3) void k_gemm(
    const __hip_bfloat16* __restrict__ A,   // [R][D] bf16 (scanned x)
    const float* __restrict__ c,            // [D] fp32 circulant kernel
    const float* __restrict__ x,            // [R][D] fp32
    const float* __restrict__ gate,         // [1]
    float* __restrict__ out)                // [R][D] fp32
{
    __shared__ __align__(16) __hip_bfloat16 sA[128 * 64];
    __shared__ __align__(16) __hip_bfloat16 rs[8][RSN];  // 8 shifted reversed rings
    __shared__ float cs[Dd];

    const int tid = threadIdx.x;
    const int wave = tid >> 6;
    const int lane = tid & 63;

    // XCD-grouped mapping on flat grid (id%8 assumed XCD round-robin).
    const int id  = blockIdx.x;        // 0..511 (flat grid)
    const int xcd = id & 7;
    const int rr  = id >> 3;           // 0..63
    const int tn  = rr & 7;            // tile_n index
    const int gg  = rr >> 3;           // 0..7
    const int tile_m = (xcd * 8 + gg) * 128;
    const int tile_n = tn * 128;

    // stage c (4 KB) into LDS, then build the 8 shifted reversed rings
    #pragma unroll
    for (int j = 0; j < 4; ++j) cs[tid + j * 256] = c[tid + j * 256];
    __syncthreads();
    #pragma unroll
    for (int s = 0; s < 8; ++s)
        for (int t = tid; t < RSN; t += 256)
            rs[s][t] = __float2bfloat16(cs[(-(t + s)) & (Dd - 1)]);
    // (rs visible to all after the first K-step barrier below)

    const int wm = (wave & 1) * 64;
    const int wn = (wave >> 1) * 64;

    f32x16 acc[2][2];
    #pragma unroll
    for (int i = 0; i < 2; ++i)
        #pragma unroll
        for (int j = 0; j < 2; ++j)
            #pragma unroll
            for (int e = 0; e < 16; ++e)
                acc[i][j][e] = 0.f;

    const int r8 = lane >> 3;
    const int gchunk = (lane & 7) ^ (r8 & 7);
    const int fm  = lane & 31;         // fragment m/n index
    const int fsw = fm & 7;            // row-part of the A read swizzle
    const int fc0 = lane >> 5;         // logical chunk low bit (k half)

    // global B column indices for this lane (per sn)
    const int ng0 = tile_n + wn + fm;

    for (int k0 = 0; k0 < Dd; k0 += 64) {
        __syncthreads();               // prior reads complete (also ring build)
        #pragma unroll
        for (int j = 0; j < 4; ++j) {
            const int row = wave * 32 + j * 8;  // wave-uniform
            async16(A + (size_t)(tile_m + row + r8) * Dd + k0 + gchunk * 8,
                    &sA[row * 64]);
        }
        __syncthreads();               // drain vmcnt -> A tile visible

        #pragma unroll
        for (int kh = 0; kh < 4; ++kh) {
            const int ck = k0 + (kh * 2 + fc0) * 8;
            bf16x8 af[2], bfr[2];
            #pragma unroll
            for (int sm = 0; sm < 2; ++sm)
                af[sm] = *(const bf16x8*)
                    &sA[(wm + sm * 32 + fm) * 64 + ((kh * 2 + fc0) ^ fsw) * 8];
            #pragma unroll
            for (int sn = 0; sn < 2; ++sn) {
                const int bi = (ck - (ng0 + sn * 32)) & (Dd - 1);
                bfr[sn] = *(const bf16x8*)&rs[bi & 7][bi & ~7];
            }
            #pragma unroll
            for (int sm = 0; sm < 2; ++sm)
                #pragma unroll
                for (int sn = 0; sn < 2; ++sn)
                    acc[sm][sn] = __builtin_amdgcn_mfma_f32_32x32x16_bf16(
                        af[sm], bfr[sn], acc[sm][sn], 0, 0, 0);
        }
    }

    // C/D layout (R7-verified): col = lane&31, row = (reg&3)+8*(reg>>2)+4*(lane>>5)
    const float g = gate[0];
    #pragma unroll
    for (int sm = 0; sm < 2; ++sm) {
        #pragma unroll
        for (int sn = 0; sn < 2; ++sn) {
            const int colg = tile_n + wn + sn * 32 + (lane & 31);
            #pragma unroll
            for (int g1 = 0; g1 < 4; ++g1) {
                const int row0 = tile_m + wm + sm * 32 + g1 * 8 + (lane >> 5) * 4;
                #pragma unroll
                for (int r0 = 0; r0 < 4; ++r0) {
                    const size_t off = (size_t)(row0 + r0) * Dd + colg;
                    out[off] = fmaf(g, acc[sm][sn][g1 * 4 + r0], x[off]);
                }
            }
        }
    }
}

// ---------------------------------------------------------------------------
extern "C" void kernel_launch(void* const* d_in, const int* in_sizes, int n_in,
                              void* d_out, int out_size, void* d_ws, size_t ws_size,
                              hipStream_t stream) {
    const float* x      = (const float*)d_in[0];
    const float* bind   = (const float*)d_in[1];
    const float* unbind = (const float*)d_in[2];
    const float* gate   = (const float*)d_in[3];
    const float* decay  = (const float*)d_in[4];
    float* out = (float*)d_out;

    // workspace layout (~16.8 MB)
    char* ws = (char*)d_ws;
    __hip_bfloat16* xs = (__hip_bfloat16*)ws;                  // 16.8 MB
    float* c = (float*)(ws + (size_t)Rr * Dd * 2);             // 4 KB

    k_scan<<<dim3(SCB + CBL), dim3(256), 0, stream>>>(x, bind, unbind, decay, xs, c);
    k_gemm<<<dim3(512),       dim3(256), 0, stream>>>(xs, c, x, gate, out);
}